// Round 8
// baseline (771.459 us; speedup 1.0000x reference)
//
#include <hip/hip_runtime.h>
#include <math.h>

#define HF 100
#define WFD 160
#define CIN 512
#define CONV_C 512
#define NPIX (HF*WFD)           // 16000
#define NBOX (NPIX*9)           // 144000
#define PRE_NMS 6000
#define POST_NMS 300
#define NEGV (-1.0e9f)
#define IMG_H 1600.0f
#define IMG_W 2560.0f
#define NHBINS 32768
#define NWORDS 94               // ceil(6000/64)
#define NSORT 6016              // 94*64

// padded X: 102 rows x 162 cols x 512 ch
#define PR 102
#define PC 162
#define NPAD ((size_t)PR*PC*512)   // 8,460,288 ushorts per array

typedef __attribute__((ext_vector_type(8))) _Float16 half8;
typedef __attribute__((ext_vector_type(4))) float floatx4;

__device__ __forceinline__ unsigned short f2h_hi(float x) {
    _Float16 h = (_Float16)x;
    return __builtin_bit_cast(unsigned short, h);
}
__device__ __forceinline__ unsigned short f2h_lo(float x, unsigned short hbits) {
    _Float16 h = __builtin_bit_cast(_Float16, hbits);
    _Float16 l = (_Float16)((x - (float)h) * 2048.0f);   // scaled residual: stays normal
    return __builtin_bit_cast(unsigned short, l);
}

#define GLL16(g, l) __builtin_amdgcn_global_load_lds( \
    (const __attribute__((address_space(1))) void*)(g), \
    (__attribute__((address_space(3))) void*)(l), 16, 0, 0)

// ---- workspace layout (units: floats) ----
static const size_t OLOG  = 0;                              // logits 16000*48 = 768,000 floats
static const size_t OXH   = (size_t)NPIX * CONV_C;          // Xh ushorts; dead after conv
static const size_t OXL   = OXH + NPAD / 2;                 // Xl ushorts; dead after conv
static const size_t OWH   = OXL + NPAD / 2;                 // fp16 [9][n=512][k=512]
static const size_t OWL   = OWH + (size_t)9*512*512/2;
static const size_t ORAW  = OWL + (size_t)9*512*512/2;
static const size_t ONMS  = ORAW + NBOX;
static const size_t OPY1  = ONMS + NBOX;
static const size_t OPX1  = OPY1 + NBOX;
static const size_t OPY2  = OPX1 + NBOX;
static const size_t OPX2  = OPY2 + NBOX;
static const size_t OHIST = OPX2 + NBOX;                    // 32768 uints
static const size_t OCNT  = OHIST + NHBINS;                 // 4 ints
static const size_t OPAR  = OCNT + 4;                       // 2 ints
static const size_t OCS   = OPAR + 2;                       // 6000
static const size_t OCY1  = OCS + PRE_NMS;
static const size_t OCX1  = OCY1 + PRE_NMS;
static const size_t OCY2  = OCX1 + PRE_NMS;
static const size_t OCX2  = OCY2 + PRE_NMS;
static const size_t OW2H  = OCX2 + PRE_NMS;                 // 48*512 ushorts = 12288 floats
static const size_t OW2L  = OW2H + 12288;
// overlays (X regions, dead after conv_mfma):
static const size_t OMASK = OXH;                            // u64[6016*94] = 1.131M floats <= 2.115M
static const size_t OSY1  = OXL;                            // 6016 each, 5 arrays
static const size_t OSX1  = OSY1 + NSORT;
static const size_t OSY2  = OSX1 + NSORT;
static const size_t OSX2  = OSY2 + NSORT;
static const size_t OSAR  = OSX2 + NSORT;

// ============================================================
// split X (fp32) -> padded fp16 hi + scaled-lo
// ============================================================
__global__ __launch_bounds__(256) void split_x(
    const float* __restrict__ X,
    unsigned short* __restrict__ Xh, unsigned short* __restrict__ Xl)
{
    const int idx = blockIdx.x * 256 + threadIdx.x;
    const int p = idx >> 7;
    const int kq = (idx & 127) * 4;
    const float4 v = *(const float4*)(X + (size_t)p * 512 + kq);
    const int r = p / WFD, c = p % WFD;
    const size_t dst = ((size_t)(r + 1) * PC + (c + 1)) * 512 + kq;
    float vv[4] = { v.x, v.y, v.z, v.w };
    unsigned short h[4], lo[4];
    #pragma unroll
    for (int u = 0; u < 4; ++u) {
        h[u]  = f2h_hi(vv[u]);
        lo[u] = f2h_lo(vv[u], h[u]);
    }
    uint2 ph, pl;
    ph.x = (unsigned)h[0]  | ((unsigned)h[1]  << 16);
    ph.y = (unsigned)h[2]  | ((unsigned)h[3]  << 16);
    pl.x = (unsigned)lo[0] | ((unsigned)lo[1] << 16);
    pl.y = (unsigned)lo[2] | ((unsigned)lo[3] << 16);
    *(uint2*)(Xh + dst) = ph;
    *(uint2*)(Xl + dst) = pl;
}

// ============================================================
// split + transpose W1 [dydx][k][n] fp32 -> Wh/Wl [dydx][n][k] fp16
// ============================================================
__global__ __launch_bounds__(256) void split_w(
    const float* __restrict__ W1,
    unsigned short* __restrict__ Wh, unsigned short* __restrict__ Wl)
{
    __shared__ unsigned short Lh[64 * 64];
    __shared__ unsigned short Ll[64 * 64];
    const int t = threadIdx.x;
    const int dydx = blockIdx.x >> 6;
    const int rem  = blockIdx.x & 63;
    const int k0 = (rem >> 3) * 64, n0 = (rem & 7) * 64;

    #pragma unroll
    for (int i = 0; i < 4; ++i) {
        const int f = t + 256 * i;
        const int row = f >> 4;
        const int cp  = (f & 15) * 4;
        const float4 v = *(const float4*)(W1 + ((size_t)(dydx * 512 + k0 + row)) * 512 + n0 + cp);
        float vv[4] = { v.x, v.y, v.z, v.w };
        #pragma unroll
        for (int u = 0; u < 4; ++u) {
            const unsigned short h = f2h_hi(vv[u]);
            Lh[(cp + u) * 64 + row] = h;
            Ll[(cp + u) * 64 + row] = f2h_lo(vv[u], h);
        }
    }
    __syncthreads();
    const int n  = t >> 2;
    const int kp = (t & 3) * 16;
    const size_t gbase = ((size_t)(dydx * 512 + n0 + n)) * 512 + k0 + kp;
    *(uint4*)(Wh + gbase)     = *(const uint4*)(Lh + n * 64 + kp);
    *(uint4*)(Wh + gbase + 8) = *(const uint4*)(Lh + n * 64 + kp + 8);
    *(uint4*)(Wl + gbase)     = *(const uint4*)(Ll + n * 64 + kp);
    *(uint4*)(Wl + gbase + 8) = *(const uint4*)(Ll + n * 64 + kp + 8);
}

// ============================================================
// split head weights: Wc[512][9] + Wr[512][36] -> [n=48][k=512] fp16 hi/lo
// ============================================================
__global__ __launch_bounds__(256) void split_w2(
    const float* __restrict__ Wc, const float* __restrict__ Wr,
    unsigned short* __restrict__ W2h, unsigned short* __restrict__ W2l)
{
    const int i = blockIdx.x * 256 + threadIdx.x;
    if (i >= 48 * 512) return;
    const int n = i >> 9, k = i & 511;
    float v = 0.f;
    if (n < 9) v = Wc[k * 9 + n];
    else if (n < 45) v = Wr[k * 36 + (n - 9)];
    const unsigned short h = f2h_hi(v);
    W2h[i] = h;
    W2l[i] = f2h_lo(v, h);
}

// ============================================================
// conv 3x3 512->512, split-fp16 3-pass MFMA.
// R8: (a) k0-outer / dydx-inner loop order — per-k0 working set fits L2;
//     (b) fused head mini-GEMM epilogue: y-tile -> fp16 hi/lo in LDS,
//     128x48 partial logits vs this block's 128-oc W2 slice, atomicAdd.
// ============================================================
__global__ __launch_bounds__(256, 2) void conv_mfma(
    const unsigned short* __restrict__ Xh, const unsigned short* __restrict__ Xl,
    const unsigned short* __restrict__ Wh, const unsigned short* __restrict__ Wl,
    const unsigned short* __restrict__ W2h, const unsigned short* __restrict__ W2l,
    const float* __restrict__ b1, float* __restrict__ logits)
{
    __shared__ alignas(16) unsigned short S[32768];   // 64 KB
    unsigned short* Ah = S;                // 128*32
    unsigned short* Al = S + 4096;
    unsigned short* Bh = S + 8192;
    unsigned short* Bl = S + 12288;
    unsigned short* Yth = S;               // epilogue overlay: 128*128
    unsigned short* Ytl = S + 16384;

    const int tid = threadIdx.x;
    const int w = tid >> 6, l = tid & 63;
    const int wy = w >> 1, wx = w & 1;

    const int bx = blockIdx.x;
    const int q = bx & 7, s5 = bx >> 3;
    const int tile = (q < 5) ? (q * 16 + s5) : (80 + (q - 5) * 15 + s5);
    const int pm0 = tile * 128, oc0 = blockIdx.y * 128;

    int aoff[2], boff[2], ldsOff[2];
    #pragma unroll
    for (int i = 0; i < 2; ++i) {
        const int m = w * 32 + i * 16 + (l >> 2);
        const int p = pm0 + m;
        const int r = p / WFD, c = p % WFD;
        aoff[i] = ((r + 1) * PC + (c + 1)) * 512 + (l & 3) * 8;
        boff[i] = (oc0 + m) * 512 + (l & 3) * 8;
        ldsOff[i] = (w * 32 + i * 16) * 32;
    }

    int afrag[4], bfrag[4];
    #pragma unroll
    for (int i = 0; i < 4; ++i) {
        afrag[i] = (wy * 64 + i * 16 + (l & 15)) * 32 + (l >> 4) * 8;
        bfrag[i] = (wx * 64 + i * 16 + (l & 15)) * 32 + (l >> 4) * 8;
    }

    floatx4 acc[4][4], accL[4][4];
    #pragma unroll
    for (int j = 0; j < 4; ++j) {
        const float bv = b1[oc0 + wx * 64 + j * 16 + (l & 15)];
        #pragma unroll
        for (int i = 0; i < 4; ++i) {
            acc[i][j][0] = bv; acc[i][j][1] = bv; acc[i][j][2] = bv; acc[i][j][3] = bv;
            accL[i][j][0] = 0.f; accL[i][j][1] = 0.f; accL[i][j][2] = 0.f; accL[i][j][3] = 0.f;
        }
    }

    for (int k0 = 0; k0 < 512; k0 += 32) {
        for (int dydx = 0; dydx < 9; ++dydx) {
            const int dy = dydx / 3 - 1, dx = dydx % 3 - 1;
            const int dA = (dy * PC + dx) * 512;
            const int dB = dydx * (512 * 512);
            __syncthreads();
            #pragma unroll
            for (int i = 0; i < 2; ++i) {
                GLL16(Xh + aoff[i] + dA + k0, Ah + ldsOff[i]);
                GLL16(Xl + aoff[i] + dA + k0, Al + ldsOff[i]);
                GLL16(Wh + boff[i] + dB + k0, Bh + ldsOff[i]);
                GLL16(Wl + boff[i] + dB + k0, Bl + ldsOff[i]);
            }
            __syncthreads();
            half8 fah[4], fal[4], fbh[4], fbl[4];
            #pragma unroll
            for (int i = 0; i < 4; ++i) {
                fah[i] = *(const half8*)(Ah + afrag[i]);
                fal[i] = *(const half8*)(Al + afrag[i]);
                fbh[i] = *(const half8*)(Bh + bfrag[i]);
                fbl[i] = *(const half8*)(Bl + bfrag[i]);
            }
            #pragma unroll
            for (int i = 0; i < 4; ++i)
                #pragma unroll
                for (int j = 0; j < 4; ++j) {
                    acc[i][j]  = __builtin_amdgcn_mfma_f32_16x16x32_f16(fah[i], fbh[j], acc[i][j], 0, 0, 0);
                    accL[i][j] = __builtin_amdgcn_mfma_f32_16x16x32_f16(fal[i], fbh[j], accL[i][j], 0, 0, 0);
                    accL[i][j] = __builtin_amdgcn_mfma_f32_16x16x32_f16(fah[i], fbl[j], accL[i][j], 0, 0, 0);
                }
        }
    }

    // ---- fused head epilogue ----
    __syncthreads();   // main-loop LDS reads done; reuse S as Yt
    #pragma unroll
    for (int i = 0; i < 4; ++i) {
        const int r0i = wy * 64 + i * 16 + (l >> 4) * 4;
        #pragma unroll
        for (int j = 0; j < 4; ++j) {
            const int c0 = wx * 64 + j * 16 + (l & 15);
            #pragma unroll
            for (int r = 0; r < 4; ++r) {
                const float yv = fmaxf(acc[i][j][r] + accL[i][j][r] * 4.8828125e-4f, 0.f);
                const unsigned short h = f2h_hi(yv);
                Yth[(r0i + r) * 128 + c0] = h;
                Ytl[(r0i + r) * 128 + c0] = f2h_lo(yv, h);
            }
        }
    }
    __syncthreads();

    // mini-GEMM: wave w handles pixel-row frags {2w, 2w+1}; k = this block's 128 oc
    #pragma unroll
    for (int j = 0; j < 3; ++j) {
        floatx4 hacc[2], haccL[2];
        #pragma unroll
        for (int i = 0; i < 2; ++i) {
            hacc[i][0] = 0.f; hacc[i][1] = 0.f; hacc[i][2] = 0.f; hacc[i][3] = 0.f;
            haccL[i] = hacc[i];
        }
        #pragma unroll
        for (int kk = 0; kk < 4; ++kk) {
            const int koff = kk * 32 + (l >> 4) * 8;
            const half8 fbh = *(const half8*)(W2h + (j * 16 + (l & 15)) * 512 + oc0 + koff);
            const half8 fbl = *(const half8*)(W2l + (j * 16 + (l & 15)) * 512 + oc0 + koff);
            #pragma unroll
            for (int i = 0; i < 2; ++i) {
                const int m = (2 * w + i) * 16 + (l & 15);
                const half8 fay = *(const half8*)(Yth + m * 128 + koff);
                const half8 fyl = *(const half8*)(Ytl + m * 128 + koff);
                hacc[i]  = __builtin_amdgcn_mfma_f32_16x16x32_f16(fay, fbh, hacc[i], 0, 0, 0);
                haccL[i] = __builtin_amdgcn_mfma_f32_16x16x32_f16(fyl, fbh, haccL[i], 0, 0, 0);
                haccL[i] = __builtin_amdgcn_mfma_f32_16x16x32_f16(fay, fbl, haccL[i], 0, 0, 0);
            }
        }
        #pragma unroll
        for (int i = 0; i < 2; ++i) {
            const int prow = pm0 + (2 * w + i) * 16 + (l >> 4) * 4;
            const int col = j * 16 + (l & 15);
            #pragma unroll
            for (int r = 0; r < 4; ++r)
                atomicAdd(&logits[(size_t)(prow + r) * 48 + col],
                          hacc[i][r] + haccL[i][r] * 4.8828125e-4f);
        }
    }
}

// ============================================================
// decode: bias + softmax + anchor decode + clip + hist. One thread/pixel.
// ============================================================
__global__ __launch_bounds__(256) void decode_k(
    const float* __restrict__ logits,
    const float* __restrict__ bc, const float* __restrict__ br,
    const float* __restrict__ anch,
    float* __restrict__ out_scores, float* __restrict__ out_deltas,
    float* __restrict__ rawS, float* __restrict__ nmsS,
    float* __restrict__ pY1, float* __restrict__ pX1,
    float* __restrict__ pY2, float* __restrict__ pX2,
    unsigned int* __restrict__ hist)
{
    const int p = blockIdx.x * 256 + threadIdx.x;
    if (p >= NPIX) return;
    const float* lg = logits + (size_t)p * 48;

    float ac[9], arr[36];
    #pragma unroll
    for (int a = 0; a < 9; ++a) ac[a] = lg[a] + bc[a];
    #pragma unroll
    for (int j = 0; j < 36; ++j) arr[j] = lg[9 + j] + br[j];

    float m = ac[0];
    #pragma unroll
    for (int a = 1; a < 9; ++a) m = fmaxf(m, ac[a]);
    float s = 0.f, e[9];
    #pragma unroll
    for (int a = 0; a < 9; ++a) { e[a] = expf(ac[a] - m); s += e[a]; }
    #pragma unroll
    for (int a = 0; a < 9; ++a) e[a] = e[a] / s;

    #pragma unroll
    for (int a = 0; a < 9; ++a) out_scores[p * 9 + a] = e[a];
    #pragma unroll
    for (int a = 0; a < 9; ++a)
        *(float4*)(out_deltas + (size_t)p * 36 + 4 * a) =
            make_float4(arr[4*a], arr[4*a+1], arr[4*a+2], arr[4*a+3]);

    #pragma unroll
    for (int a = 0; a < 9; ++a) {
        const float4 an = *(const float4*)(anch + (size_t)p * 36 + 4 * a);
        const float cty = an.x + arr[4*a]   * an.z;
        const float ctx = an.y + arr[4*a+1] * an.w;
        const float szy = an.z * expf(arr[4*a+2]);
        const float szx = an.w * expf(arr[4*a+3]);
        float y1 = fmaxf(cty - 0.5f * szy, 0.f);
        float x1 = fmaxf(ctx - 0.5f * szx, 0.f);
        float y2 = fminf(cty + 0.5f * szy, IMG_H);
        float x2 = fminf(ctx + 0.5f * szx, IMG_W);
        const bool valid = ((y2 - y1) >= 16.f) && ((x2 - x1) >= 16.f);
        const int idx = p * 9 + a;
        rawS[idx] = e[a];
        nmsS[idx] = valid ? e[a] : NEGV;
        pY1[idx] = y1; pX1[idx] = x1; pY2[idx] = y2; pX2[idx] = x2;
        atomicAdd(&hist[__float_as_uint(e[a]) >> 15], 1u);
    }
}

// ============================================================
// select_k: parallel suffix-scan over histogram
// ============================================================
__global__ __launch_bounds__(1024) void select_k(const unsigned int* __restrict__ hist,
                                                 int* __restrict__ params)
{
    __shared__ unsigned int ps[1024];
    const int t = threadIdx.x;
    unsigned int loc[32];
    unsigned int sum = 0;
    #pragma unroll 4
    for (int i = 0; i < 32; ++i) { loc[i] = hist[t * 32 + i]; sum += loc[i]; }
    ps[t] = sum;
    for (int off = 1; off < 1024; off <<= 1) {
        __syncthreads();
        const unsigned int add = (t + off < 1024) ? ps[t + off] : 0u;
        __syncthreads();
        ps[t] += add;
    }
    __syncthreads();
    const unsigned int above = (t < 1023) ? ps[t + 1] : 0u;
    if (above < (unsigned)PRE_NMS && ps[t] >= (unsigned)PRE_NMS) {
        unsigned int cum = above;
        for (int j = 31; j >= 0; --j) {
            const unsigned int h = loc[j];
            if (cum + h >= (unsigned)PRE_NMS) {
                params[0] = t * 32 + j;
                params[1] = PRE_NMS - (int)cum;
                break;
            }
            cum += h;
        }
    }
}

__global__ void compact_k(const float* __restrict__ rawS, const float* __restrict__ nmsS,
                          const float* __restrict__ pY1, const float* __restrict__ pX1,
                          const float* __restrict__ pY2, const float* __restrict__ pX2,
                          const int* __restrict__ params, int* __restrict__ cnts,
                          float* __restrict__ cS,
                          float* __restrict__ cY1, float* __restrict__ cX1,
                          float* __restrict__ cY2, float* __restrict__ cX2)
{
    const int i = blockIdx.x * 256 + threadIdx.x;
    if (i >= NBOX) return;
    const int b = (int)(__float_as_uint(rawS[i]) >> 15);
    const int bin = params[0];
    const int need = params[1];
    int pos = -1;
    if (b > bin) {
        pos = atomicAdd(&cnts[0], 1);
    } else if (b == bin) {
        const int t2 = atomicAdd(&cnts[1], 1);
        if (t2 < need) pos = atomicAdd(&cnts[0], 1);
    }
    if (pos >= 0) {
        const float sv = nmsS[i];
        cS[pos]  = sv;
        cY1[pos] = pY1[i]; cX1[pos] = pX1[i];
        cY2[pos] = pY2[i]; cX2[pos] = pX2[i];
        if (sv > NEGV * 0.5f) atomicAdd(&cnts[2], 1);
    }
}

// ============================================================
// sort_k: bitonic sort by score desc (exact 64-bit keys), gathers SoA boxes
// ============================================================
__global__ __launch_bounds__(1024) void sort_k(
    const float* __restrict__ cS,
    const float* __restrict__ cY1, const float* __restrict__ cX1,
    const float* __restrict__ cY2, const float* __restrict__ cX2,
    float* __restrict__ sY1, float* __restrict__ sX1,
    float* __restrict__ sY2, float* __restrict__ sX2,
    float* __restrict__ sAr)
{
    __shared__ unsigned long long keys[8192];
    const int t = threadIdx.x;
    for (int i = t; i < 8192; i += 1024) {
        unsigned long long k;
        if (i < PRE_NMS) {
            const unsigned b = __float_as_uint(cS[i]);
            const unsigned m = (b & 0x80000000u) ? ~b : (b | 0x80000000u);
            k = ((unsigned long long)(~m) << 32) | (unsigned)i;
        } else {
            k = ~0ULL;
        }
        keys[i] = k;
    }
    for (int kk = 2; kk <= 8192; kk <<= 1) {
        for (int j = kk >> 1; j > 0; j >>= 1) {
            __syncthreads();
            for (int t4 = t; t4 < 4096; t4 += 1024) {
                const int i  = ((t4 & ~(j - 1)) << 1) | (t4 & (j - 1));
                const int p2 = i | j;
                const bool up = ((i & kk) == 0);
                const unsigned long long a = keys[i], b = keys[p2];
                const bool sw = up ? (a > b) : (a < b);
                if (sw) { keys[i] = b; keys[p2] = a; }
            }
        }
    }
    __syncthreads();
    for (int i = t; i < NSORT; i += 1024) {
        if (i < PRE_NMS) {
            const int j = (int)(keys[i] & 0xFFFFFFFFu);
            const float y1 = cY1[j], x1 = cX1[j], y2 = cY2[j], x2 = cX2[j];
            sY1[i] = y1; sX1[i] = x1; sY2[i] = y2; sX2[i] = x2;
            sAr[i] = (y2 - y1) * (x2 - x1);
        } else {
            sY1[i] = 0.f; sX1[i] = 0.f; sY2[i] = 0.f; sX2[i] = 0.f; sAr[i] = 0.f;
        }
    }
}

// ============================================================
// mask_k: suppression bitmask. mask[r*94+bj] bit u = iou(r, bj*64+u)>0.7
// ============================================================
__global__ __launch_bounds__(64) void mask_k(
    const float* __restrict__ sY1, const float* __restrict__ sX1,
    const float* __restrict__ sY2, const float* __restrict__ sX2,
    const float* __restrict__ sAr, unsigned long long* __restrict__ mask)
{
    __shared__ float ly1[64], lx1[64], ly2[64], lx2[64], lar[64];
    const int t = threadIdx.x;
    const int c = blockIdx.y * 64 + t;
    ly1[t] = sY1[c]; lx1[t] = sX1[c]; ly2[t] = sY2[c]; lx2[t] = sX2[c]; lar[t] = sAr[c];
    __syncthreads();
    const int r = blockIdx.x * 64 + t;
    const float ry1 = sY1[r], rx1 = sX1[r], ry2 = sY2[r], rx2 = sX2[r], rar = sAr[r];
    unsigned long long bits = 0ULL;
    #pragma unroll 8
    for (int u = 0; u < 64; ++u) {
        const float iy1 = fmaxf(ry1, ly1[u]);
        const float ix1 = fmaxf(rx1, lx1[u]);
        const float iy2 = fminf(ry2, ly2[u]);
        const float ix2 = fminf(rx2, lx2[u]);
        const float inter = fmaxf(iy2 - iy1, 0.f) * fmaxf(ix2 - ix1, 0.f);
        const float iou = inter / (lar[u] + rar - inter + 1e-8f);
        bits |= (iou > 0.7f) ? (1ULL << u) : 0ULL;
    }
    mask[(size_t)r * NWORDS + blockIdx.y] = bits;
}

// ============================================================
// scan3_k: greedy scan, per-pick direct row loads (L2-resident mask),
// skips fully-suppressed chunks. One wave, no barriers.
// ============================================================
__global__ __launch_bounds__(64) void scan3_k(
    const float* __restrict__ sY1, const float* __restrict__ sX1,
    const float* __restrict__ sY2, const float* __restrict__ sX2,
    const unsigned long long* __restrict__ mask, const int* __restrict__ cnts,
    float* __restrict__ outP)
{
    const int l = threadIdx.x;
    const int nvRaw = cnts[2];
    const int nv = nvRaw < PRE_NMS ? nvRaw : PRE_NMS;
    unsigned long long r0 = 0ULL, r1 = 0ULL;   // lane l owns remv words l, 64+l
    int n = 0;
    for (int w = 0; w < NWORDS && n < POST_NMS; ++w) {
        const int base = w << 6;
        if (base >= nv) break;
        unsigned long long cw = (w < 64) ? __shfl(r0, w, 64) : __shfl(r1, w - 64, 64);
        const int lim = nv - base;
        if (lim < 64) cw |= (~0ULL << lim);
        if (cw == ~0ULL) continue;
        const int ci = base + l;
        const float v1 = sY1[ci], v2 = sX1[ci], v3 = sY2[ci], v4 = sX2[ci];
        while (cw != ~0ULL && n < POST_NMS) {
            const int b = (int)__builtin_ctzll(~cw);
            const float by1 = __shfl(v1, b, 64);
            const float bx1 = __shfl(v2, b, 64);
            const float by2 = __shfl(v3, b, 64);
            const float bx2 = __shfl(v4, b, 64);
            if (l == 0) {
                outP[4 * n + 0] = by1; outP[4 * n + 1] = bx1;
                outP[4 * n + 2] = by2; outP[4 * n + 3] = bx2;
            }
            ++n;
            cw |= (1ULL << b);
            if (n >= POST_NMS) break;
            const unsigned long long* row = mask + (size_t)(base + b) * NWORDS;
            const unsigned long long m0 = row[l];
            const unsigned long long m1 = (l < NWORDS - 64) ? row[64 + l] : 0ULL;
            r0 |= m0; r1 |= m1;
            cw |= (w < 64) ? __shfl(m0, w, 64) : __shfl(m1, w - 64, 64);
        }
    }
    for (int idx = 4 * n + l; idx < 4 * POST_NMS; idx += 64) outP[idx] = 0.f;
}

// ============================================================
extern "C" void kernel_launch(void* const* d_in, const int* in_sizes, int n_in,
                              void* d_out, int out_size, void* d_ws, size_t ws_size,
                              hipStream_t stream)
{
    const float* X    = (const float*)d_in[1];
    const float* anch = (const float*)d_in[2];
    const float* W1   = (const float*)d_in[3];
    const float* b1   = (const float*)d_in[4];
    const float* Wc   = (const float*)d_in[5];
    const float* bc   = (const float*)d_in[6];
    const float* Wr   = (const float*)d_in[7];
    const float* br   = (const float*)d_in[8];

    float* out = (float*)d_out;
    float* ws  = (float*)d_ws;

    float* logits = ws + OLOG;
    unsigned short* Xh = (unsigned short*)(ws + OXH);
    unsigned short* Xl = (unsigned short*)(ws + OXL);
    unsigned short* Wh = (unsigned short*)(ws + OWH);
    unsigned short* Wl = (unsigned short*)(ws + OWL);
    float* rawS = ws + ORAW;
    float* nmsS = ws + ONMS;
    float* pY1  = ws + OPY1;
    float* pX1  = ws + OPX1;
    float* pY2  = ws + OPY2;
    float* pX2  = ws + OPX2;
    unsigned int* hist = (unsigned int*)(ws + OHIST);
    int* cnts   = (int*)(ws + OCNT);
    int* params = (int*)(ws + OPAR);
    float* cS   = ws + OCS;
    float* cY1  = ws + OCY1;
    float* cX1  = ws + OCX1;
    float* cY2  = ws + OCY2;
    float* cX2  = ws + OCX2;
    unsigned short* W2h = (unsigned short*)(ws + OW2H);
    unsigned short* W2l = (unsigned short*)(ws + OW2L);
    float* sY1  = ws + OSY1;
    float* sX1  = ws + OSX1;
    float* sY2  = ws + OSY2;
    float* sX2  = ws + OSX2;
    float* sAr  = ws + OSAR;
    unsigned long long* mask = (unsigned long long*)(ws + OMASK);

    float* out_scores = out;
    float* out_deltas = out + NBOX;
    float* out_props  = out + (size_t)NBOX * 5;

    hipMemsetAsync(hist, 0, (NHBINS + 8) * sizeof(unsigned int), stream);
    hipMemsetAsync(logits, 0, (size_t)NPIX * 48 * sizeof(float), stream);
    hipMemsetAsync(Xh, 0, 2 * NPAD * sizeof(unsigned short), stream);

    split_x<<<8000, 256, 0, stream>>>(X, Xh, Xl);
    split_w<<<576, 256, 0, stream>>>(W1, Wh, Wl);
    split_w2<<<96, 256, 0, stream>>>(Wc, Wr, W2h, W2l);

    conv_mfma<<<dim3(125, 4), 256, 0, stream>>>(Xh, Xl, Wh, Wl, W2h, W2l, b1, logits);

    decode_k<<<(NPIX + 255) / 256, 256, 0, stream>>>(logits, bc, br, anch,
        out_scores, out_deltas, rawS, nmsS, pY1, pX1, pY2, pX2, hist);

    select_k<<<1, 1024, 0, stream>>>(hist, params);
    compact_k<<<(NBOX + 255) / 256, 256, 0, stream>>>(
        rawS, nmsS, pY1, pX1, pY2, pX2, params, cnts, cS, cY1, cX1, cY2, cX2);

    sort_k<<<1, 1024, 0, stream>>>(cS, cY1, cX1, cY2, cX2,
                                   sY1, sX1, sY2, sX2, sAr);
    mask_k<<<dim3(NWORDS, NWORDS), 64, 0, stream>>>(sY1, sX1, sY2, sX2, sAr, mask);
    scan3_k<<<1, 64, 0, stream>>>(sY1, sX1, sY2, sX2, mask, cnts, out_props);
}